// Round 17
// baseline (757.037 us; speedup 1.0000x reference)
//
#include <hip/hip_runtime.h>
#include <math.h>
#include <stdint.h>

typedef __bf16 bf16_t;
typedef __bf16 bf16x4 __attribute__((ext_vector_type(4)));
typedef __bf16 bf16x8 __attribute__((ext_vector_type(8)));
typedef float  f32x4  __attribute__((ext_vector_type(4)));

#define D_MODEL 2048
#define T_SEQ   2048
#define BATCH   2
#define NROWS   (BATCH*T_SEQ)   // 4096
#define NHEAD   16
#define HDIM    128
#define KVH     4
#define KVD     (KVH*HDIM)      // 512
#define FDIM    8192
#define QKVN    3072            // fused q(2048)+k(512)+v(512)

__device__ __forceinline__ bf16x8 mk8(bf16x4 lo, bf16x4 hi) {
  union { bf16x4 h[2]; bf16x8 v; } u;
  u.h[0] = lo; u.h[1] = hi; return u.v;
}

__device__ __forceinline__ void gl16(const bf16_t* g, bf16_t* l) {
  __builtin_amdgcn_global_load_lds(
      (const uint32_t __attribute__((address_space(1)))*)g,
      (uint32_t __attribute__((address_space(3)))*)l, 16, 0, 0);
}

// ---------------- weight transpose+convert: in [K][N] f32 -> out [N][K] bf16 ----------------
__global__ __launch_bounds__(256)
void transpose_w(const float* __restrict__ in, bf16_t* __restrict__ outT, int K, int N)
{
  __shared__ __align__(16) bf16_t t[64][72];
  const int tid = threadIdx.x;
  const int k0 = blockIdx.y * 64, n0 = blockIdx.x * 64;
  const int tr = tid >> 4, tc = (tid & 15) * 4;
#pragma unroll
  for (int i = 0; i < 4; ++i) {
    f32x4 v = *(const f32x4*)(in + (size_t)(k0 + tr + 16 * i) * N + n0 + tc);
#pragma unroll
    for (int e = 0; e < 4; ++e) t[tr + 16 * i][tc + e] = (bf16_t)v[e];
  }
  __syncthreads();
#pragma unroll
  for (int s = 0; s < 2; ++s) {
    const int c = s * 256 + tid;
    const int n = c >> 3, c8 = (c & 7) * 8;
    bf16x8 o;
#pragma unroll
    for (int e = 0; e < 8; ++e) o[e] = t[c8 + e][n];
    *(bf16x8*)(outT + (size_t)(n0 + n) * K + k0 + c8) = o;
  }
}

__global__ __launch_bounds__(256)
void concat_bias(const float* __restrict__ a, const float* __restrict__ b,
                 const float* __restrict__ c, float* __restrict__ dst)
{
  const int i = blockIdx.x * 256 + threadIdx.x;
  if (i >= QKVN) return;
  dst[i] = (i < 2048) ? a[i] : (i < 2560) ? b[i - 2048] : c[i - 2560];
}

// ---------------- LayerNorm ----------------
template<typename TI>
__global__ __launch_bounds__(256)
void ln_kernel(const TI* __restrict__ x, const float* __restrict__ g,
               const float* __restrict__ b, bf16_t* __restrict__ out)
{
  const int row = blockIdx.x;
  const int tid = threadIdx.x;
  const TI* xr = x + (size_t)row * D_MODEL;
  float vals[8];
  if constexpr (sizeof(TI) == 4) {
    f32x4 v0 = *(const f32x4*)(xr + tid * 8);
    f32x4 v1 = *(const f32x4*)(xr + tid * 8 + 4);
#pragma unroll
    for (int e = 0; e < 4; ++e) { vals[e] = v0[e]; vals[4 + e] = v1[e]; }
  } else {
    bf16x8 v = *(const bf16x8*)(xr + tid * 8);
#pragma unroll
    for (int e = 0; e < 8; ++e) vals[e] = (float)v[e];
  }
  float s = 0.f, s2 = 0.f;
#pragma unroll
  for (int e = 0; e < 8; ++e) { s += vals[e]; s2 += vals[e] * vals[e]; }
#pragma unroll
  for (int off = 1; off < 64; off <<= 1) { s += __shfl_xor(s, off); s2 += __shfl_xor(s2, off); }
  __shared__ float red[8];
  const int wid = tid >> 6, lane = tid & 63;
  if (lane == 0) { red[wid] = s; red[4 + wid] = s2; }
  __syncthreads();
  s  = red[0] + red[1] + red[2] + red[3];
  s2 = red[4] + red[5] + red[6] + red[7];
  const float mean = s * (1.f / D_MODEL);
  const float var  = s2 * (1.f / D_MODEL) - mean * mean;
  const float rstd = rsqrtf(var + 1e-5f);
  f32x4 g0 = *(const f32x4*)(g + tid * 8), g1 = *(const f32x4*)(g + tid * 8 + 4);
  f32x4 b0 = *(const f32x4*)(b + tid * 8), b1 = *(const f32x4*)(b + tid * 8 + 4);
  bf16x8 o;
#pragma unroll
  for (int e = 0; e < 4; ++e) {
    o[e]     = (bf16_t)((vals[e]     - mean) * rstd * g0[e] + b0[e]);
    o[4 + e] = (bf16_t)((vals[4 + e] - mean) * rstd * g1[e] + b1[e]);
  }
  *(bf16x8*)(out + (size_t)row * D_MODEL + tid * 8) = o;
}

// ---- fused ln2 + fln ----
__global__ __launch_bounds__(256)
void ln2_fused(const bf16_t* __restrict__ x, const float* __restrict__ g2,
               const float* __restrict__ b2, const float* __restrict__ gf,
               const float* __restrict__ bf_, bf16_t* __restrict__ rout,
               bf16_t* __restrict__ hout)
{
  const int row = blockIdx.x;
  const int tid = threadIdx.x;
  const int wid = tid >> 6, lane = tid & 63;
  __shared__ float red[8];
  const bf16_t* xr = x + (size_t)row * D_MODEL;
  bf16x8 v = *(const bf16x8*)(xr + tid * 8);
  float vals[8]; float s = 0.f, s2 = 0.f;
#pragma unroll
  for (int e = 0; e < 8; ++e) { vals[e] = (float)v[e]; s += vals[e]; s2 += vals[e] * vals[e]; }
#pragma unroll
  for (int off = 1; off < 64; off <<= 1) { s += __shfl_xor(s, off); s2 += __shfl_xor(s2, off); }
  if (lane == 0) { red[wid] = s; red[4 + wid] = s2; }
  __syncthreads();
  s  = red[0] + red[1] + red[2] + red[3];
  s2 = red[4] + red[5] + red[6] + red[7];
  float mean = s * (1.f / D_MODEL);
  float var  = s2 * (1.f / D_MODEL) - mean * mean;
  float rstd = rsqrtf(var + 1e-5f);
  f32x4 ga0 = *(const f32x4*)(g2 + tid * 8), ga1 = *(const f32x4*)(g2 + tid * 8 + 4);
  f32x4 ba0 = *(const f32x4*)(b2 + tid * 8), ba1 = *(const f32x4*)(b2 + tid * 8 + 4);
  float y[8];
#pragma unroll
  for (int e = 0; e < 4; ++e) {
    y[e]     = (vals[e]     - mean) * rstd * ga0[e] + ba0[e];
    y[4 + e] = (vals[4 + e] - mean) * rstd * ga1[e] + ba1[e];
  }
  bf16x8 o1;
#pragma unroll
  for (int e = 0; e < 8; ++e) o1[e] = (bf16_t)y[e];
  *(bf16x8*)(rout + (size_t)row * D_MODEL + tid * 8) = o1;
  s = 0.f; s2 = 0.f;
#pragma unroll
  for (int e = 0; e < 8; ++e) { s += y[e]; s2 += y[e] * y[e]; }
#pragma unroll
  for (int off = 1; off < 64; off <<= 1) { s += __shfl_xor(s, off); s2 += __shfl_xor(s2, off); }
  __syncthreads();
  if (lane == 0) { red[wid] = s; red[4 + wid] = s2; }
  __syncthreads();
  s  = red[0] + red[1] + red[2] + red[3];
  s2 = red[4] + red[5] + red[6] + red[7];
  mean = s * (1.f / D_MODEL);
  var  = s2 * (1.f / D_MODEL) - mean * mean;
  rstd = rsqrtf(var + 1e-5f);
  f32x4 gb0 = *(const f32x4*)(gf + tid * 8), gb1 = *(const f32x4*)(gf + tid * 8 + 4);
  f32x4 bb0 = *(const f32x4*)(bf_ + tid * 8), bb1 = *(const f32x4*)(bf_ + tid * 8 + 4);
  bf16x8 o2;
#pragma unroll
  for (int e = 0; e < 4; ++e) {
    o2[e]     = (bf16_t)((y[e]     - mean) * rstd * gb0[e] + bb0[e]);
    o2[4 + e] = (bf16_t)((y[4 + e] - mean) * rstd * gb1[e] + bb1[e]);
  }
  *(bf16x8*)(hout + (size_t)row * D_MODEL + tid * 8) = o2;
}

enum { EPI_NONE = 0, EPI_RES = 1, EPI_SILU = 2, EPI_MUL = 3 };

// XCD-aware bijective block swizzle (requires nwg % 8 == 0 — all launches comply)
__device__ __forceinline__ void xcd_swz(int BMv, int BNv, int& m0, int& n0) {
  const int nbx = gridDim.x, nwg = nbx * gridDim.y;
  int flat = blockIdx.y * nbx + blockIdx.x;
  flat = (flat & 7) * (nwg >> 3) + (flat >> 3);
  m0 = (flat / nbx) * BMv; n0 = (flat % nbx) * BNv;
}

// ======= FUSED W1+W2 GEMM on the gemm8p schedule (round-16) =======
// out = silu(A@W1t^T + b1) * (A@W2t^T + b2), bf16. Tile BM=256 x BN=128 (per
// matrix), 8 waves (2M x 4N, 32 cols/wave/matrix), BK=64, 4 phases:
// {kh0*B1, kh0*B2, kh1*B1, kh1*B2}, 16 MFMA each. Stage rotation / vmcnt(6)
// IDENTICAL to the 10-round-proven gemm8p (stage groups are 2 gl16 each:
// SA = 2x A-chunk, SB12 = B1-chunk + B2-chunk). LDS 128 KB, acc = 128 VGPR
// (same as gemm8p). Saves: A staged once (not twice), no gate write+re-read.
__global__ __launch_bounds__(512, 2)
void gemm_w12f(const bf16_t* __restrict__ A, const bf16_t* __restrict__ B1t,
               const bf16_t* __restrict__ B2t, const float* __restrict__ bias1,
               const float* __restrict__ bias2, bf16_t* __restrict__ out,
               int M, int N, int K)
{
  __shared__ __align__(16) bf16_t As[2][2][256 * 32];   // 64 KB
  __shared__ __align__(16) bf16_t B1s[2][2][128 * 32];  // 32 KB
  __shared__ __align__(16) bf16_t B2s[2][2][128 * 32];  // 32 KB
  const int tid = threadIdx.x, lane = tid & 63, wid = tid >> 6;
  const int wr = wid >> 2, wc = wid & 3;
  const int l16 = lane & 15, lq = lane >> 4;
  int m0, n0; xcd_swz(256, 128, m0, n0);

  const bf16_t* aP[2]; int aL[2];
#pragma unroll
  for (int s = 0; s < 2; ++s) {
    const int c = s * 512 + tid;
    const int row = c >> 2, pos = c & 3;
    aP[s] = A + (size_t)(m0 + row) * K + (pos ^ ((row >> 1) & 3)) * 8;
    aL[s] = (s * 512 + wid * 64) * 8;
  }
  const bf16_t* b1P; const bf16_t* b2P; int bL;
  {
    const int row = tid >> 2, pos = tid & 3;
    const int g = pos ^ ((row >> 1) & 3);
    b1P = B1t + (size_t)(n0 + row) * K + g * 8;
    b2P = B2t + (size_t)(n0 + row) * K + g * 8;
    bL = (wid * 64) * 8;
  }

  int offA[8];
#pragma unroll
  for (int i = 0; i < 8; ++i) {
    const int r = wr * 128 + i * 16 + l16;
    offA[i] = r * 32 + ((lq ^ ((r >> 1) & 3)) * 8);
  }
  int offB[2];
#pragma unroll
  for (int jj = 0; jj < 2; ++jj) {
    const int r = wc * 32 + jj * 16 + l16;
    offB[jj] = r * 32 + ((lq ^ ((r >> 1) & 3)) * 8);
  }

  f32x4 acc1[8][2], acc2[8][2];
#pragma unroll
  for (int i = 0; i < 8; ++i)
#pragma unroll
    for (int j = 0; j < 2; ++j) {
      acc1[i][j] = (f32x4){0.f, 0.f, 0.f, 0.f};
      acc2[i][j] = (f32x4){0.f, 0.f, 0.f, 0.f};
    }

  auto SA = [&](int t, int bb, int kh) {
#pragma unroll
    for (int s = 0; s < 2; ++s) gl16(aP[s] + t * 64 + kh * 32, &As[bb][kh][aL[s]]);
  };
  auto SB12 = [&](int t, int bb, int kh) {
    gl16(b1P + t * 64 + kh * 32, &B1s[bb][kh][bL]);
    gl16(b2P + t * 64 + kh * 32, &B2s[bb][kh][bL]);
  };
#define BAR_()  __builtin_amdgcn_s_barrier()
#define LGKM_() do { asm volatile("s_waitcnt lgkmcnt(0)" ::: "memory"); \
                     __builtin_amdgcn_sched_barrier(0); } while (0)

  const int nt = K >> 6;
  SA(0, 0, 0); SB12(0, 0, 0); SA(0, 0, 1); SB12(0, 0, 1);
  if (nt > 1) { SA(1, 1, 0); SB12(1, 1, 0); SA(1, 1, 1); }
  if (nt > 2) asm volatile("s_waitcnt vmcnt(6)" ::: "memory");
  else        asm volatile("s_waitcnt vmcnt(0)" ::: "memory");
  BAR_();

  for (int t = 0; t < nt; ++t) {
    const int b = t & 1, ob = b ^ 1;
    const bool s1 = (t + 1 < nt), s2 = (t + 2 < nt);
    bf16x8 af[8], bf0, bf1;
    // phase 0: kh0 x B1 (reads first, then stage — round-8 order)
#pragma unroll
    for (int i = 0; i < 8; ++i) af[i] = *(const bf16x8*)(&As[b][0][offA[i]]);
    bf0 = *(const bf16x8*)(&B1s[b][0][offB[0]]);
    bf1 = *(const bf16x8*)(&B1s[b][0][offB[1]]);
    if (s1) SB12(t + 1, ob, 1);
    BAR_(); LGKM_();
    __builtin_amdgcn_s_setprio(1);
#pragma unroll
    for (int i = 0; i < 8; ++i) {
      acc1[i][0] = __builtin_amdgcn_mfma_f32_16x16x32_bf16(af[i], bf0, acc1[i][0], 0, 0, 0);
      acc1[i][1] = __builtin_amdgcn_mfma_f32_16x16x32_bf16(af[i], bf1, acc1[i][1], 0, 0, 0);
    }
    __builtin_amdgcn_s_setprio(0);
    BAR_();
    // phase 1: kh0 x B2 (A regs reused)
    bf0 = *(const bf16x8*)(&B2s[b][0][offB[0]]);
    bf1 = *(const bf16x8*)(&B2s[b][0][offB[1]]);
    if (s2) SA(t + 2, b, 0);
    BAR_(); LGKM_();
    __builtin_amdgcn_s_setprio(1);
#pragma unroll
    for (int i = 0; i < 8; ++i) {
      acc2[i][0] = __builtin_amdgcn_mfma_f32_16x16x32_bf16(af[i], bf0, acc2[i][0], 0, 0, 0);
      acc2[i][1] = __builtin_amdgcn_mfma_f32_16x16x32_bf16(af[i], bf1, acc2[i][1], 0, 0, 0);
    }
    __builtin_amdgcn_s_setprio(0);
    BAR_();
    // phase 2: kh1 x B1
#pragma unroll
    for (int i = 0; i < 8; ++i) af[i] = *(const bf16x8*)(&As[b][1][offA[i]]);
    bf0 = *(const bf16x8*)(&B1s[b][1][offB[0]]);
    bf1 = *(const bf16x8*)(&B1s[b][1][offB[1]]);
    if (s2) SB12(t + 2, b, 0);
    BAR_(); LGKM_();
    __builtin_amdgcn_s_setprio(1);
#pragma unroll
    for (int i = 0; i < 8; ++i) {
      acc1[i][0] = __builtin_amdgcn_mfma_f32_16x16x32_bf16(af[i], bf0, acc1[i][0], 0, 0, 0);
      acc1[i][1] = __builtin_amdgcn_mfma_f32_16x16x32_bf16(af[i], bf1, acc1[i][1], 0, 0, 0);
    }
    __builtin_amdgcn_s_setprio(0);
    BAR_();
    // phase 3: kh1 x B2
    bf0 = *(const bf16x8*)(&B2s[b][1][offB[0]]);
    bf1 = *(const bf16x8*)(&B2s[b][1][offB[1]]);
    if (s2) SA(t + 2, b, 1);
    BAR_(); LGKM_();
    __builtin_amdgcn_s_setprio(1);
#pragma unroll
    for (int i = 0; i < 8; ++i) {
      acc2[i][0] = __builtin_amdgcn_mfma_f32_16x16x32_bf16(af[i], bf0, acc2[i][0], 0, 0, 0);
      acc2[i][1] = __builtin_amdgcn_mfma_f32_16x16x32_bf16(af[i], bf1, acc2[i][1], 0, 0, 0);
    }
    __builtin_amdgcn_s_setprio(0);
    if (t < nt - 2) asm volatile("s_waitcnt vmcnt(6)" ::: "memory");
    else            asm volatile("s_waitcnt vmcnt(0)" ::: "memory");
    BAR_();
  }
#undef BAR_
#undef LGKM_

  // ---- epilogue: silu(g)*h in f32 through per-wave LDS scratch, coalesced store ----
  float* sc = (float*)(&As[0][0][0]) + (size_t)wid * (16 * 40);   // 8 x 2.5 KB <= 64 KB
  const int rr = lane >> 2, c8 = (lane & 3) * 8;
#pragma unroll
  for (int i = 0; i < 8; ++i) {
    const int row0 = m0 + wr * 128 + i * 16;
#pragma unroll
    for (int j = 0; j < 2; ++j) {
      const int col = n0 + wc * 32 + j * 16 + l16;
      const float bb1 = bias1[col], bb2 = bias2[col];
#pragma unroll
      for (int e = 0; e < 4; ++e) {
        float g = acc1[i][j][e] + bb1;
        float h = acc2[i][j][e] + bb2;
        float c2 = fminf(fmaxf(g, -10.f), 10.f);
        sc[(lq * 4 + e) * 40 + j * 16 + l16] = (g / (1.f + __expf(-c2))) * h;
      }
    }
    asm volatile("s_waitcnt lgkmcnt(0)" ::: "memory");
    __builtin_amdgcn_sched_barrier(0);
    {
      f32x4 a0 = *(const f32x4*)(sc + rr * 40 + c8);
      f32x4 a1 = *(const f32x4*)(sc + rr * 40 + c8 + 4);
      bf16x8 o;
#pragma unroll
      for (int e = 0; e < 4; ++e) { o[e] = (bf16_t)a0[e]; o[4 + e] = (bf16_t)a1[e]; }
      *(bf16x8*)(out + (size_t)(row0 + rr) * N + n0 + wc * 32 + c8) = o;
    }
    asm volatile("s_waitcnt lgkmcnt(0)" ::: "memory");
    __builtin_amdgcn_sched_barrier(0);
  }
}

// ======= gemm3b (round-11 proven, 848 TF): 128x128, BK=32, 4 waves, 3 LDS bufs =======
template<int EPI, typename TE, typename TO>
__global__ __launch_bounds__(256, 4)
void gemm3b(const bf16_t* __restrict__ A, const bf16_t* __restrict__ Bt,
            const float* __restrict__ bias, const TE* __restrict__ extra,
            TO* __restrict__ out, int M, int N, int K)
{
  __shared__ __align__(16) bf16_t As[3][128 * 32];
  __shared__ __align__(16) bf16_t Bs[3][128 * 32];
  const int tid = threadIdx.x, lane = tid & 63, wid = tid >> 6;
  const int wr = wid >> 1, wc = wid & 1;
  const int l16 = lane & 15, lq = lane >> 4;
  int m0, n0; xcd_swz(128, 128, m0, n0);

  const bf16_t* aP[2]; const bf16_t* bP[2]; int sL[2];
#pragma unroll
  for (int s = 0; s < 2; ++s) {
    const int c = s * 256 + tid;
    const int row = c >> 2, pos = c & 3;
    const int g = pos ^ ((row >> 1) & 3);
    aP[s] = A  + (size_t)(m0 + row) * K + g * 8;
    bP[s] = Bt + (size_t)(n0 + row) * K + g * 8;
    sL[s] = (s * 256 + wid * 64) * 8;
  }

  int offA[4], offB[4];
#pragma unroll
  for (int i = 0; i < 4; ++i) {
    const int r = wr * 64 + i * 16 + l16;
    offA[i] = r * 32 + ((lq ^ ((r >> 1) & 3)) * 8);
  }
#pragma unroll
  for (int j = 0; j < 4; ++j) {
    const int r = wc * 64 + j * 16 + l16;
    offB[j] = r * 32 + ((lq ^ ((r >> 1) & 3)) * 8);
  }

  f32x4 acc[4][4];
#pragma unroll
  for (int i = 0; i < 4; ++i)
#pragma unroll
    for (int j = 0; j < 4; ++j) acc[i][j] = (f32x4){0.f, 0.f, 0.f, 0.f};

  auto STAGE = [&](int t, int b) {
    gl16(aP[0] + t * 32, &As[b][sL[0]]);
    gl16(aP[1] + t * 32, &As[b][sL[1]]);
    gl16(bP[0] + t * 32, &Bs[b][sL[0]]);
    gl16(bP[1] + t * 32, &Bs[b][sL[1]]);
  };

  const int nt = K >> 5;
  STAGE(0, 0);
  STAGE(1, 1);
  if (nt > 1) asm volatile("s_waitcnt vmcnt(4)" ::: "memory");
  else        asm volatile("s_waitcnt vmcnt(0)" ::: "memory");
  __builtin_amdgcn_s_barrier();

  int b = 0;
  for (int t = 0; t < nt; ++t) {
    bf16x8 af[4], bfr[4];
#pragma unroll
    for (int i = 0; i < 4; ++i) af[i]  = *(const bf16x8*)(&As[b][offA[i]]);
#pragma unroll
    for (int j = 0; j < 4; ++j) bfr[j] = *(const bf16x8*)(&Bs[b][offB[j]]);
    if (t + 2 < nt) {
      STAGE(t + 2, (b + 2) % 3);
      asm volatile("s_waitcnt vmcnt(4)" ::: "memory");
    } else {
      asm volatile("s_waitcnt vmcnt(0)" ::: "memory");
    }
    __builtin_amdgcn_s_barrier();
    asm volatile("s_waitcnt lgkmcnt(0)" ::: "memory");
    __builtin_amdgcn_sched_barrier(0);
    __builtin_amdgcn_s_setprio(1);
#pragma unroll
    for (int i = 0; i < 4; ++i)
#pragma unroll
      for (int j = 0; j < 4; ++j)
        acc[i][j] = __builtin_amdgcn_mfma_f32_16x16x32_bf16(af[i], bfr[j], acc[i][j], 0, 0, 0);
    __builtin_amdgcn_s_setprio(0);
    __builtin_amdgcn_s_barrier();
    b = (b + 1) % 3;
  }

  // ---- epilogue ----
  if constexpr (sizeof(TO) == 2) {
    float* sc = (float*)(&As[0][0]) + (size_t)wid * (16 * 72);
    const int rr = lane >> 3, cc8 = (lane & 7) * 8;
#pragma unroll
    for (int i = 0; i < 4; ++i) {
      const int row0 = m0 + wr * 64 + i * 16;
#pragma unroll
      for (int j = 0; j < 4; ++j) {
        const float bb = bias[n0 + wc * 64 + j * 16 + l16];
#pragma unroll
        for (int e = 0; e < 4; ++e) {
          float vv = acc[i][j][e] + bb;
          if (EPI == EPI_SILU) { float c2 = fminf(fmaxf(vv, -10.f), 10.f); vv = vv / (1.f + __expf(-c2)); }
          sc[(lq * 4 + e) * 72 + j * 16 + l16] = vv;
        }
      }
      asm volatile("s_waitcnt lgkmcnt(0)" ::: "memory");
      __builtin_amdgcn_sched_barrier(0);
#pragma unroll
      for (int q = 0; q < 2; ++q) {
        const int row = row0 + rr + q * 8;
        const size_t base = (size_t)row * N + n0 + wc * 64 + cc8;
        f32x4 a0 = *(const f32x4*)(sc + (rr + q * 8) * 72 + cc8);
        f32x4 a1 = *(const f32x4*)(sc + (rr + q * 8) * 72 + cc8 + 4);
        bf16x8 o;
        if constexpr (EPI == EPI_RES) {
          if constexpr (sizeof(TE) == 4) {
            f32x4 x0 = *(const f32x4*)((const float*)extra + base);
            f32x4 x1 = *(const f32x4*)((const float*)extra + base + 4);
#pragma unroll
            for (int e = 0; e < 4; ++e) { o[e] = (bf16_t)(a0[e] + x0[e]); o[4 + e] = (bf16_t)(a1[e] + x1[e]); }
          } else {
            bf16x8 x8 = *(const bf16x8*)((const bf16_t*)extra + base);
#pragma unroll
            for (int e = 0; e < 4; ++e) { o[e] = (bf16_t)(a0[e] + (float)x8[e]); o[4 + e] = (bf16_t)(a1[e] + (float)x8[4 + e]); }
          }
        } else if constexpr (EPI == EPI_MUL) {
          bf16x8 x8 = *(const bf16x8*)((const bf16_t*)extra + base);
#pragma unroll
          for (int e = 0; e < 4; ++e) { o[e] = (bf16_t)(a0[e] * (float)x8[e]); o[4 + e] = (bf16_t)(a1[e] * (float)x8[4 + e]); }
        } else {
#pragma unroll
          for (int e = 0; e < 4; ++e) { o[e] = (bf16_t)a0[e]; o[4 + e] = (bf16_t)a1[e]; }
        }
        *(bf16x8*)((bf16_t*)out + base) = o;
      }
      asm volatile("s_waitcnt lgkmcnt(0)" ::: "memory");
      __builtin_amdgcn_sched_barrier(0);
    }
  } else {
#pragma unroll
    for (int j = 0; j < 4; ++j) {
      const int col = n0 + wc * 64 + j * 16 + l16;
      const float bb = bias[col];
#pragma unroll
      for (int i = 0; i < 4; ++i) {
        const int row0 = m0 + wr * 64 + i * 16 + lq * 4;
#pragma unroll
        for (int e = 0; e < 4; ++e) {
          const size_t idx = (size_t)(row0 + e) * N + col;
          float vv = acc[i][j][e] + bb;
          if (EPI == EPI_RES)       vv += (float)extra[idx];
          else if (EPI == EPI_SILU) { float c2 = fminf(fmaxf(vv, -10.f), 10.f); vv = vv / (1.f + __expf(-c2)); }
          else if (EPI == EPI_MUL)  vv *= (float)extra[idx];
          out[idx] = (TO)vv;
        }
      }
    }
  }
}

// ------- fallback GEMM (f32 weights, round-1 proven) -------
template<int EPI, typename TE, typename TO>
__global__ __launch_bounds__(256)
void gemm_kernel(const bf16_t* __restrict__ A, const float* __restrict__ W,
                 const float* __restrict__ bias, const TE* __restrict__ extra,
                 TO* __restrict__ out, int M, int N, int K)
{
  __shared__ bf16_t As[128][40];
  __shared__ bf16_t Bs[128][40];
  const int tid  = threadIdx.x;
  const int lane = tid & 63, wid = tid >> 6;
  const int wr = wid >> 1, wc = wid & 1;
  const int l16 = lane & 15, lq = lane >> 4;
  const int m0 = blockIdx.y * 128, n0 = blockIdx.x * 128;

  f32x4 acc[4][4];
#pragma unroll
  for (int i = 0; i < 4; ++i)
#pragma unroll
    for (int j = 0; j < 4; ++j) acc[i][j] = (f32x4){0.f, 0.f, 0.f, 0.f};

  const int ar = tid >> 1, ah = tid & 1;
  const int kk = tid & 31, cc = tid >> 5;

  for (int k0 = 0; k0 < K; k0 += 32) {
    const bf16_t* asrc = A + (size_t)(m0 + ar) * K + k0 + ah * 16;
    *(bf16x8*)(&As[ar][ah * 16])     = *(const bf16x8*)(asrc);
    *(bf16x8*)(&As[ar][ah * 16 + 8]) = *(const bf16x8*)(asrc + 8);
    const float* wsrc = W + (size_t)(k0 + kk) * N + n0;
#pragma unroll
    for (int it = 0; it < 2; ++it) {
      const int c = cc * 8 + it * 64;
      f32x4 wa = *(const f32x4*)(wsrc + c);
      f32x4 wb = *(const f32x4*)(wsrc + c + 4);
#pragma unroll
      for (int e = 0; e < 4; ++e) {
        Bs[c + e][kk]     = (bf16_t)wa[e];
        Bs[c + 4 + e][kk] = (bf16_t)wb[e];
      }
    }
    __syncthreads();
    bf16x8 af[4], bfr[4];
#pragma unroll
    for (int i = 0; i < 4; ++i) {
      const bf16_t* p = &As[wr * 64 + i * 16 + l16][lq * 4];
      af[i] = mk8(*(const bf16x4*)p, *(const bf16x4*)(p + 16));
    }
#pragma unroll
    for (int j = 0; j < 4; ++j) {
      const bf16_t* p = &Bs[wc * 64 + j * 16 + l16][lq * 4];
      bfr[j] = mk8(*(const bf16x4*)p, *(const bf16x4*)(p + 16));
    }
#pragma unroll
    for (int i = 0; i < 4; ++i)
#pragma unroll
      for (int j = 0; j < 4; ++j)
        acc[i][j] = __builtin_amdgcn_mfma_f32_16x16x32_bf16(af[i], bfr[j], acc[i][j], 0, 0, 0);
    __syncthreads();
  }

#pragma unroll
  for (int j = 0; j < 4; ++j) {
    const int col = n0 + wc * 64 + j * 16 + l16;
    const float bb = bias[col];
#pragma unroll
    for (int i = 0; i < 4; ++i) {
      const int row0 = m0 + wr * 64 + i * 16 + lq * 4;
#pragma unroll
      for (int e = 0; e < 4; ++e) {
        const size_t idx = (size_t)(row0 + e) * N + col;
        float vv = acc[i][j][e] + bb;
        if (EPI == EPI_RES)       vv += (float)extra[idx];
        else if (EPI == EPI_SILU) { float c2 = fminf(fmaxf(vv, -10.f), 10.f); vv = vv / (1.f + __expf(-c2)); }
        else if (EPI == EPI_MUL)  vv *= (float)extra[idx];
        out[idx] = (TO)vv;
      }
    }
  }
}

// ---- Flash attention v4: QBLK=128 (8 waves), swapped QK^T, pipelined K/V staging ----
__global__ __launch_bounds__(512)
void attn_kernel(const bf16_t* __restrict__ q, const bf16_t* __restrict__ k,
                 const bf16_t* __restrict__ v, bf16_t* __restrict__ ctx,
                 int q_ld, int kv_ld)
{
  __shared__ __align__(16) bf16_t Ks[2][64 * 128];  // 32 KB, chunk-XOR swizzled
  __shared__ __align__(16) bf16_t Vt[128][72];      // 18.4 KB, [hd][kv] transposed

  const int tid = threadIdx.x, lane = tid & 63, wid = tid >> 6;  // wid 0..7
  const int l16 = lane & 15, lq = lane >> 4;
  const int bh = blockIdx.y;
  const int b = bh >> 4, h = bh & 15;
  const int kh = h >> 2;
  const float scale = 0.08838834764831845f;

  const int vr = tid & 63, vo = (tid >> 6) * 8;

  for (int pass = 0; pass < 2; ++pass) {
    const int qt = pass ? blockIdx.x : (15 - blockIdx.x);
    const int qbase = qt * 128;
    const int qrow = qbase + wid * 16 + l16;

    const bf16_t* qp = q + (size_t)(b * T_SEQ + qrow) * q_ld + h * HDIM;
    bf16x8 bq[4];
#pragma unroll
    for (int s = 0; s < 4; ++s) bq[s] = *(const bf16x8*)(qp + s * 32 + lq * 8);

    float m_r = -1e30f, l_r = 0.f;
    f32x4 acc_o[8];
#pragma unroll
    for (int jh = 0; jh < 8; ++jh) acc_o[jh] = (f32x4){0.f, 0.f, 0.f, 0.f};

    const int ntiles = (qbase + 128) >> 6;

    bf16x8 vregs[2];
#pragma unroll
    for (int it = 0; it < 2; ++it) {
      const int c = it * 512 + tid;
      const int kvr = c >> 4, pos = c & 15;
      gl16(k + (size_t)(b * T_SEQ + kvr) * kv_ld + kh * HDIM + (pos ^ (kvr & 7)) * 8,
           &Ks[0][(it * 512 + wid * 64) * 8]);
    }
#pragma unroll
    for (int it = 0; it < 2; ++it)
      vregs[it] = *(const bf16x8*)(v + (size_t)(b * T_SEQ + vr) * kv_ld + kh * HDIM + vo + it * 64);

    int cur = 0;
    for (int t = 0; t < ntiles; ++t) {
      const int kb = t * 64;
#pragma unroll
      for (int it = 0; it < 2; ++it) {
#pragma unroll
        for (int e = 0; e < 8; ++e) Vt[vo + it * 64 + e][vr] = vregs[it][e];
      }
      if (t + 1 < ntiles) {
        const int kb2 = kb + 64;
#pragma unroll
        for (int it = 0; it < 2; ++it) {
          const int c = it * 512 + tid;
          const int kvr = c >> 4, pos = c & 15;
          gl16(k + (size_t)(b * T_SEQ + kb2 + kvr) * kv_ld + kh * HDIM + (pos ^ (kvr & 7)) * 8,
               &Ks[cur ^ 1][(it * 512 + wid * 64) * 8]);
        }
#pragma unroll
        for (int it = 0; it < 2; ++it)
          vregs[it] = *(const bf16x8*)(v + (size_t)(b * T_SEQ + kb2 + vr) * kv_ld + kh * HDIM + vo + it * 64);
      }
      asm volatile("s_waitcnt lgkmcnt(0)" ::: "memory");
      __builtin_amdgcn_s_barrier();
      __builtin_amdgcn_sched_barrier(0);

      f32x4 sf[4];
#pragma unroll
      for (int j = 0; j < 4; ++j) {
        sf[j] = (f32x4){0.f, 0.f, 0.f, 0.f};
        const int kvr = j * 16 + l16;
#pragma unroll
        for (int s = 0; s < 4; ++s) {
          bf16x8 ak = *(const bf16x8*)(&Ks[cur][kvr * 128 + (((s * 4 + lq) ^ (kvr & 7)) * 8)]);
          sf[j] = __builtin_amdgcn_mfma_f32_16x16x32_bf16(ak, bq[s], sf[j], 0, 0, 0);
        }
      }

      float p[4][4];
      float tmax = -1e30f;
#pragma unroll
      for (int j = 0; j < 4; ++j)
#pragma unroll
        for (int e = 0; e < 4; ++e) {
          const int kvc = kb + j * 16 + lq * 4 + e;
          float sv = sf[j][e] * scale;
          sv = fminf(fmaxf(sv, -100.f), 100.f);
          if (kvc > qrow) sv = -1e30f;
          p[j][e] = sv;
          tmax = fmaxf(tmax, sv);
        }
      tmax = fmaxf(tmax, __shfl_xor(tmax, 16));
      tmax = fmaxf(tmax, __shfl_xor(tmax, 32));
      const float mnew = fmaxf(m_r, tmax);
      const float resc = __expf(m_r - mnew);
      m_r = mnew;
      float rsum = 0.f;
#pragma unroll
      for (int j = 0; j < 4; ++j)
#pragma unroll
        for (int e = 0; e < 4; ++e) {
          p[j][e] = __expf(p[j][e] - m_r);
          rsum += p[j][e];
        }
      rsum += __shfl_xor(rsum, 16);
      rsum += __shfl_xor(rsum, 32);
      l_r = l_r * resc + rsum;

      float resc4[4];
#pragma unroll
      for (int e = 0; e < 4; ++e) resc4[e] = __shfl(resc, lq * 4 + e);
#pragma unroll
      for (int jh = 0; jh < 8; ++jh)
#pragma unroll
        for (int e = 0; e < 4; ++e) acc_o[jh][e] *= resc4[e];

      bf16x8 pa[2];
#pragma unroll
      for (int sk = 0; sk < 2; ++sk) {
        bf16x4 lo, hi;
#pragma unroll
        for (int e = 0; e < 4; ++e) { lo[e] = (bf16_t)p[2 * sk][e]; hi[e] = (bf16_t)p[2 * sk + 1][e]; }
        pa[sk] = mk8(lo, hi);
      }
#pragma unroll
      for (int jh = 0; jh < 8; ++jh) {
#pragma unroll
        for (int sk = 0; sk < 2; ++sk) {
          const bf16_t* pV = &Vt[jh * 16 + l16][sk * 32 + lq * 4];
          bf16x8 bv2 = mk8(*(const bf16x4*)pV, *(const bf16x4*)(pV + 16));
          acc_o[jh] = __builtin_amdgcn_mfma_f32_16x16x32_bf16(pa[sk], bv2, acc_o[jh], 0, 0, 0);
        }
      }
      __builtin_amdgcn_s_barrier();
      cur ^= 1;
    }

    float l4[4];
#pragma unroll
    for (int e = 0; e < 4; ++e) l4[e] = __shfl(l_r, lq * 4 + e);
    bf16_t* op = ctx + (size_t)(b * T_SEQ + qbase + wid * 16) * D_MODEL + h * HDIM;
#pragma unroll
    for (int jh = 0; jh < 8; ++jh)
#pragma unroll
      for (int e = 0; e < 4; ++e)
        op[(size_t)(lq * 4 + e) * D_MODEL + jh * 16 + l16] = (bf16_t)(acc_o[jh][e] / l4[e]);
  }
}

// ---------------- launcher ----------------
extern "C" void kernel_launch(void* const* d_in, const int* in_sizes, int n_in,
                              void* d_out, int out_size, void* d_ws, size_t ws_size,
                              hipStream_t stream)
{
  const float* x   = (const float*)d_in[0];
  const float* Wq  = (const float*)d_in[2];
  const float* bq  = (const float*)d_in[3];
  const float* Wk  = (const float*)d_in[4];
  const float* bk  = (const float*)d_in[5];
  const float* Wv  = (const float*)d_in[6];
  const float* bv  = (const float*)d_in[7];
  const float* Wo  = (const float*)d_in[8];
  const float* bo  = (const float*)d_in[9];
  const float* g1  = (const float*)d_in[10];
  const float* b1n = (const float*)d_in[11];
  const float* g2  = (const float*)d_in[12];
  const float* b2n = (const float*)d_in[13];
  const float* gf  = (const float*)d_in[14];
  const float* bfn = (const float*)d_in[15];
  const float* W1  = (const float*)d_in[16];
  const float* bb1 = (const float*)d_in[17];
  const float* W2  = (const float*)d_in[18];
  const float* bb2 = (const float*)d_in[19];
  const float* W3  = (const float*)d_in[20];
  const float* bb3 = (const float*)d_in[21];
  float* out = (float*)d_out;

  char* ws = (char*)d_ws;
  size_t off = 0;
  auto alloc = [&](size_t bytes) -> void* {
    void* p = ws + off; off += (bytes + 255) & ~(size_t)255; return p;
  };
  const dim3 blk(256);

  // ---- fast-path workspace layout ----
  bf16_t* Wt_qkv = (bf16_t*)alloc((size_t)QKVN * D_MODEL * 2);
  bf16_t* Wt_o   = (bf16_t*)alloc((size_t)D_MODEL * D_MODEL * 2);
  bf16_t* Wt1    = (bf16_t*)alloc((size_t)FDIM * D_MODEL * 2);
  bf16_t* Wt2    = (bf16_t*)alloc((size_t)FDIM * D_MODEL * 2);
  bf16_t* Wt3    = (bf16_t*)alloc((size_t)D_MODEL * FDIM * 2);
  float*  bqkv   = (float*)alloc((size_t)QKVN * 4);
  bf16_t* hbuf   = (bf16_t*)alloc((size_t)NROWS * D_MODEL * 2);
  bf16_t* qkvbuf = (bf16_t*)alloc((size_t)NROWS * QKVN * 2);
  bf16_t* rbuf   = (bf16_t*)alloc((size_t)NROWS * D_MODEL * 2);
  bf16_t* h2buf  = (bf16_t*)alloc((size_t)NROWS * D_MODEL * 2);
  const size_t core = off;

  if (core <= ws_size) {
    size_t avail = ws_size - core;
    int chunk = (int)((avail / ((size_t)FDIM * 2)) & ~(size_t)255);
    bf16_t* gbuf;
    if (chunk >= 256) { gbuf = (bf16_t*)(ws + core); if (chunk > NROWS) chunk = NROWS; }
    else              { gbuf = qkvbuf; chunk = 1536; }  // 1536 % 256 == 0
    bf16_t* x1buf = qkvbuf;

    transpose_w<<<dim3(32, 32),  blk, 0, stream>>>(Wq, Wt_qkv, D_MODEL, 2048);
    transpose_w<<<dim3(8, 32),   blk, 0, stream>>>(Wk, Wt_qkv + (size_t)2048 * D_MODEL, D_MODEL, 512);
    transpose_w<<<dim3(8, 32),   blk, 0, stream>>>(Wv, Wt_qkv + (size_t)2560 * D_MODEL, D_MODEL, 512);
    transpose_w<<<dim3(32, 32),  blk, 0, stream>>>(Wo, Wt_o, D_MODEL, D_MODEL);
    transpose_w<<<dim3(128, 32), blk, 0, stream>>>(W1, Wt1, D_MODEL, FDIM);
    transpose_w<<<dim3(128, 32), blk, 0, stream>>>(W2, Wt2, D_MODEL, FDIM);
    transpose_w<<<dim3(32, 128), blk, 0, stream>>>(W3, Wt3, FDIM, D_MODEL);
    concat_bias<<<12, blk, 0, stream>>>(bq, bk, bv, bqkv);

    ln_kernel<float><<<NROWS, blk, 0, stream>>>(x, g1, b1n, hbuf);
    gemm3b<EPI_NONE, bf16_t, bf16_t><<<dim3(QKVN / 128, NROWS / 128), blk, 0, stream>>>(
        hbuf, Wt_qkv, bqkv, nullptr, qkvbuf, NROWS, QKVN, D_MODEL);
    attn_kernel<<<dim3(8, 32), 512, 0, stream>>>(
        qkvbuf, qkvbuf + 2048, qkvbuf + 2560, hbuf, QKVN, QKVN);
    gemm3b<EPI_RES, float, bf16_t><<<dim3(D_MODEL / 128, NROWS / 128), blk, 0, stream>>>(
        hbuf, Wt_o, bo, x, x1buf, NROWS, D_MODEL, D_MODEL);
    ln2_fused<<<NROWS, blk, 0, stream>>>(x1buf, g2, b2n, gf, bfn, rbuf, h2buf);

    for (int r0 = 0; r0 < NROWS; r0 += chunk) {
      const int rows = (NROWS - r0 < chunk) ? (NROWS - r0) : chunk;
      gemm_w12f<<<dim3(FDIM / 128, rows / 256), 512, 0, stream>>>(
          h2buf + (size_t)r0 * D_MODEL, Wt1, Wt2, bb1, bb2, gbuf, rows, FDIM, D_MODEL);
      gemm3b<EPI_RES, bf16_t, float><<<dim3(D_MODEL / 128, rows / 128), blk, 0, stream>>>(
          gbuf, Wt3, bb3, rbuf + (size_t)r0 * D_MODEL, out + (size_t)r0 * D_MODEL, rows, D_MODEL, FDIM);
    }
    return;
  }

  // ---- fallback: round-1 proven path (f32 weights in GEMM) ----
  off = 0;
  const size_t DBYTES = (size_t)NROWS * D_MODEL * 2;
  bf16_t* fhbuf  = (bf16_t*)alloc(DBYTES);
  bf16_t* fqbuf  = (bf16_t*)alloc(DBYTES);
  bf16_t* fkbuf  = (bf16_t*)alloc((size_t)NROWS * KVD * 2);
  bf16_t* fvbuf  = (bf16_t*)alloc((size_t)NROWS * KVD * 2);
  bf16_t* frbuf  = (bf16_t*)alloc(DBYTES);
  bf16_t* fh2buf = (bf16_t*)alloc(DBYTES);
  const size_t base = off;
  size_t avail = (ws_size > base) ? (ws_size - base) : 0;
  int chunk = (int)((avail / ((size_t)FDIM * 2)) & ~(size_t)127);
  bf16_t* gbuf;
  if (chunk >= 128) { gbuf = (bf16_t*)(ws + base); if (chunk > NROWS) chunk = NROWS; }
  else              { gbuf = fqbuf; chunk = 1024; }

  ln_kernel<float><<<NROWS, blk, 0, stream>>>(x, g1, b1n, fhbuf);
  gemm_kernel<EPI_NONE, bf16_t, bf16_t><<<dim3(16, 32), blk, 0, stream>>>(fhbuf, Wq, bq, nullptr, fqbuf, NROWS, 2048, 2048);
  gemm_kernel<EPI_NONE, bf16_t, bf16_t><<<dim3(4, 32),  blk, 0, stream>>>(fhbuf, Wk, bk, nullptr, fkbuf, NROWS, 512, 2048);
  gemm_kernel<EPI_NONE, bf16_t, bf16_t><<<dim3(4, 32),  blk, 0, stream>>>(fhbuf, Wv, bv, nullptr, fvbuf, NROWS, 512, 2048);
  attn_kernel<<<dim3(8, 32), 512, 0, stream>>>(fqbuf, fkbuf, fvbuf, fhbuf, 2048, 512);
  gemm_kernel<EPI_RES, float, bf16_t><<<dim3(16, 32), blk, 0, stream>>>(fhbuf, Wo, bo, x, fqbuf, NROWS, 2048, 2048);
  ln_kernel<bf16_t><<<NROWS, blk, 0, stream>>>(fqbuf, g2, b2n, frbuf);
  ln_kernel<bf16_t><<<NROWS, blk, 0, stream>>>(frbuf, gf, bfn, fh2buf);
  for (int r0 = 0; r0 < NROWS; r0 += chunk) {
    const int rows = (NROWS - r0 < chunk) ? (NROWS - r0) : chunk;
    gemm_kernel<EPI_SILU, bf16_t, bf16_t><<<dim3(64, rows / 128), blk, 0, stream>>>(
        fh2buf + (size_t)r0 * D_MODEL, W1, bb1, nullptr, gbuf, rows, FDIM, 2048);
    gemm_kernel<EPI_MUL, bf16_t, bf16_t><<<dim3(64, rows / 128), blk, 0, stream>>>(
        fh2buf + (size_t)r0 * D_MODEL, W2, bb2, gbuf, gbuf, rows, FDIM, 2048);
    gemm_kernel<EPI_RES, bf16_t, float><<<dim3(16, rows / 128), blk, 0, stream>>>(
        gbuf, W3, bb3, frbuf + (size_t)r0 * D_MODEL, out + (size_t)r0 * D_MODEL, rows, 2048, FDIM);
  }
}

// Round 18
// 751.368 us; speedup vs baseline: 1.0075x; 1.0075x over previous
//
#include <hip/hip_runtime.h>
#include <math.h>
#include <stdint.h>

typedef __bf16 bf16_t;
typedef __bf16 bf16x4 __attribute__((ext_vector_type(4)));
typedef __bf16 bf16x8 __attribute__((ext_vector_type(8)));
typedef float  f32x4  __attribute__((ext_vector_type(4)));

#define D_MODEL 2048
#define T_SEQ   2048
#define BATCH   2
#define NROWS   (BATCH*T_SEQ)   // 4096
#define NHEAD   16
#define HDIM    128
#define KVH     4
#define KVD     (KVH*HDIM)      // 512
#define FDIM    8192
#define QKVN    3072            // fused q(2048)+k(512)+v(512)

__device__ __forceinline__ bf16x8 mk8(bf16x4 lo, bf16x4 hi) {
  union { bf16x4 h[2]; bf16x8 v; } u;
  u.h[0] = lo; u.h[1] = hi; return u.v;
}

__device__ __forceinline__ void gl16(const bf16_t* g, bf16_t* l) {
  __builtin_amdgcn_global_load_lds(
      (const uint32_t __attribute__((address_space(1)))*)g,
      (uint32_t __attribute__((address_space(3)))*)l, 16, 0, 0);
}

// ---------------- weight transpose+convert: in [K][N] f32 -> out [N][K] bf16 ----------------
__global__ __launch_bounds__(256)
void transpose_w(const float* __restrict__ in, bf16_t* __restrict__ outT, int K, int N)
{
  __shared__ __align__(16) bf16_t t[64][72];
  const int tid = threadIdx.x;
  const int k0 = blockIdx.y * 64, n0 = blockIdx.x * 64;
  const int tr = tid >> 4, tc = (tid & 15) * 4;
#pragma unroll
  for (int i = 0; i < 4; ++i) {
    f32x4 v = *(const f32x4*)(in + (size_t)(k0 + tr + 16 * i) * N + n0 + tc);
#pragma unroll
    for (int e = 0; e < 4; ++e) t[tr + 16 * i][tc + e] = (bf16_t)v[e];
  }
  __syncthreads();
#pragma unroll
  for (int s = 0; s < 2; ++s) {
    const int c = s * 256 + tid;
    const int n = c >> 3, c8 = (c & 7) * 8;
    bf16x8 o;
#pragma unroll
    for (int e = 0; e < 8; ++e) o[e] = t[c8 + e][n];
    *(bf16x8*)(outT + (size_t)(n0 + n) * K + k0 + c8) = o;
  }
}

__global__ __launch_bounds__(256)
void concat_bias(const float* __restrict__ a, const float* __restrict__ b,
                 const float* __restrict__ c, float* __restrict__ dst)
{
  const int i = blockIdx.x * 256 + threadIdx.x;
  if (i >= QKVN) return;
  dst[i] = (i < 2048) ? a[i] : (i < 2560) ? b[i - 2048] : c[i - 2560];
}

// ---------------- LayerNorm ----------------
template<typename TI>
__global__ __launch_bounds__(256)
void ln_kernel(const TI* __restrict__ x, const float* __restrict__ g,
               const float* __restrict__ b, bf16_t* __restrict__ out)
{
  const int row = blockIdx.x;
  const int tid = threadIdx.x;
  const TI* xr = x + (size_t)row * D_MODEL;
  float vals[8];
  if constexpr (sizeof(TI) == 4) {
    f32x4 v0 = *(const f32x4*)(xr + tid * 8);
    f32x4 v1 = *(const f32x4*)(xr + tid * 8 + 4);
#pragma unroll
    for (int e = 0; e < 4; ++e) { vals[e] = v0[e]; vals[4 + e] = v1[e]; }
  } else {
    bf16x8 v = *(const bf16x8*)(xr + tid * 8);
#pragma unroll
    for (int e = 0; e < 8; ++e) vals[e] = (float)v[e];
  }
  float s = 0.f, s2 = 0.f;
#pragma unroll
  for (int e = 0; e < 8; ++e) { s += vals[e]; s2 += vals[e] * vals[e]; }
#pragma unroll
  for (int off = 1; off < 64; off <<= 1) { s += __shfl_xor(s, off); s2 += __shfl_xor(s2, off); }
  __shared__ float red[8];
  const int wid = tid >> 6, lane = tid & 63;
  if (lane == 0) { red[wid] = s; red[4 + wid] = s2; }
  __syncthreads();
  s  = red[0] + red[1] + red[2] + red[3];
  s2 = red[4] + red[5] + red[6] + red[7];
  const float mean = s * (1.f / D_MODEL);
  const float var  = s2 * (1.f / D_MODEL) - mean * mean;
  const float rstd = rsqrtf(var + 1e-5f);
  f32x4 g0 = *(const f32x4*)(g + tid * 8), g1 = *(const f32x4*)(g + tid * 8 + 4);
  f32x4 b0 = *(const f32x4*)(b + tid * 8), b1 = *(const f32x4*)(b + tid * 8 + 4);
  bf16x8 o;
#pragma unroll
  for (int e = 0; e < 4; ++e) {
    o[e]     = (bf16_t)((vals[e]     - mean) * rstd * g0[e] + b0[e]);
    o[4 + e] = (bf16_t)((vals[4 + e] - mean) * rstd * g1[e] + b1[e]);
  }
  *(bf16x8*)(out + (size_t)row * D_MODEL + tid * 8) = o;
}

// ---- fused ln2 + fln ----
__global__ __launch_bounds__(256)
void ln2_fused(const bf16_t* __restrict__ x, const float* __restrict__ g2,
               const float* __restrict__ b2, const float* __restrict__ gf,
               const float* __restrict__ bf_, bf16_t* __restrict__ rout,
               bf16_t* __restrict__ hout)
{
  const int row = blockIdx.x;
  const int tid = threadIdx.x;
  const int wid = tid >> 6, lane = tid & 63;
  __shared__ float red[8];
  const bf16_t* xr = x + (size_t)row * D_MODEL;
  bf16x8 v = *(const bf16x8*)(xr + tid * 8);
  float vals[8]; float s = 0.f, s2 = 0.f;
#pragma unroll
  for (int e = 0; e < 8; ++e) { vals[e] = (float)v[e]; s += vals[e]; s2 += vals[e] * vals[e]; }
#pragma unroll
  for (int off = 1; off < 64; off <<= 1) { s += __shfl_xor(s, off); s2 += __shfl_xor(s2, off); }
  if (lane == 0) { red[wid] = s; red[4 + wid] = s2; }
  __syncthreads();
  s  = red[0] + red[1] + red[2] + red[3];
  s2 = red[4] + red[5] + red[6] + red[7];
  float mean = s * (1.f / D_MODEL);
  float var  = s2 * (1.f / D_MODEL) - mean * mean;
  float rstd = rsqrtf(var + 1e-5f);
  f32x4 ga0 = *(const f32x4*)(g2 + tid * 8), ga1 = *(const f32x4*)(g2 + tid * 8 + 4);
  f32x4 ba0 = *(const f32x4*)(b2 + tid * 8), ba1 = *(const f32x4*)(b2 + tid * 8 + 4);
  float y[8];
#pragma unroll
  for (int e = 0; e < 4; ++e) {
    y[e]     = (vals[e]     - mean) * rstd * ga0[e] + ba0[e];
    y[4 + e] = (vals[4 + e] - mean) * rstd * ga1[e] + ba1[e];
  }
  bf16x8 o1;
#pragma unroll
  for (int e = 0; e < 8; ++e) o1[e] = (bf16_t)y[e];
  *(bf16x8*)(rout + (size_t)row * D_MODEL + tid * 8) = o1;
  s = 0.f; s2 = 0.f;
#pragma unroll
  for (int e = 0; e < 8; ++e) { s += y[e]; s2 += y[e] * y[e]; }
#pragma unroll
  for (int off = 1; off < 64; off <<= 1) { s += __shfl_xor(s, off); s2 += __shfl_xor(s2, off); }
  __syncthreads();
  if (lane == 0) { red[wid] = s; red[4 + wid] = s2; }
  __syncthreads();
  s  = red[0] + red[1] + red[2] + red[3];
  s2 = red[4] + red[5] + red[6] + red[7];
  mean = s * (1.f / D_MODEL);
  var  = s2 * (1.f / D_MODEL) - mean * mean;
  rstd = rsqrtf(var + 1e-5f);
  f32x4 gb0 = *(const f32x4*)(gf + tid * 8), gb1 = *(const f32x4*)(gf + tid * 8 + 4);
  f32x4 bb0 = *(const f32x4*)(bf_ + tid * 8), bb1 = *(const f32x4*)(bf_ + tid * 8 + 4);
  bf16x8 o2;
#pragma unroll
  for (int e = 0; e < 4; ++e) {
    o2[e]     = (bf16_t)((y[e]     - mean) * rstd * gb0[e] + bb0[e]);
    o2[4 + e] = (bf16_t)((y[4 + e] - mean) * rstd * gb1[e] + bb1[e]);
  }
  *(bf16x8*)(hout + (size_t)row * D_MODEL + tid * 8) = o2;
}

enum { EPI_NONE = 0, EPI_RES = 1, EPI_SILU = 2, EPI_MUL = 3 };

// XCD-aware bijective block swizzle (requires nwg % 8 == 0 — all launches comply)
__device__ __forceinline__ void xcd_swz(int BMv, int BNv, int& m0, int& n0) {
  const int nbx = gridDim.x, nwg = nbx * gridDim.y;
  int flat = blockIdx.y * nbx + blockIdx.x;
  flat = (flat & 7) * (nwg >> 3) + (flat >> 3);
  m0 = (flat / nbx) * BMv; n0 = (flat % nbx) * BNv;
}

// ======= 8-phase GEMM (round-10 proven): BM=256 x BN=256 tile, BK=64, 8 waves =======
template<int EPI, int BM_T, typename TE, typename TO>
__global__ __launch_bounds__(512, 2)
void gemm8p(const bf16_t* __restrict__ A, const bf16_t* __restrict__ Bt,
            const float* __restrict__ bias, const TE* __restrict__ extra,
            TO* __restrict__ out, int M, int N, int K)
{
  constexpr int ALs = BM_T / 128;
  constexpr int RF  = BM_T / 32;
  __shared__ __align__(16) bf16_t As[2][2][BM_T * 32];
  __shared__ __align__(16) bf16_t Bs[2][2][256 * 32];
  const int tid = threadIdx.x, lane = tid & 63, wid = tid >> 6;
  const int wr = wid >> 2, wc = wid & 3;
  const int l16 = lane & 15, lq = lane >> 4;
  int m0, n0; xcd_swz(BM_T, 256, m0, n0);

  const bf16_t* aP[ALs]; int aL[ALs];
#pragma unroll
  for (int s = 0; s < ALs; ++s) {
    const int c = s * 512 + tid;
    const int row = c >> 2, pos = c & 3;
    aP[s] = A + (size_t)(m0 + row) * K + (pos ^ ((row >> 1) & 3)) * 8;
    aL[s] = (s * 512 + wid * 64) * 8;
  }
  const bf16_t* bP[2]; int bL[2];
#pragma unroll
  for (int s = 0; s < 2; ++s) {
    const int c = s * 512 + tid;
    const int row = c >> 2, pos = c & 3;
    bP[s] = Bt + (size_t)(n0 + row) * K + (pos ^ ((row >> 1) & 3)) * 8;
    bL[s] = (s * 512 + wid * 64) * 8;
  }

  int offA[RF];
#pragma unroll
  for (int i = 0; i < RF; ++i) {
    const int r = wr * (BM_T / 2) + i * 16 + l16;
    offA[i] = r * 32 + ((lq ^ ((r >> 1) & 3)) * 8);
  }
  int offB[4];
#pragma unroll
  for (int jj = 0; jj < 4; ++jj) {
    const int r = wc * 64 + jj * 16 + l16;
    offB[jj] = r * 32 + ((lq ^ ((r >> 1) & 3)) * 8);
  }

  f32x4 acc[RF][4];
#pragma unroll
  for (int i = 0; i < RF; ++i)
#pragma unroll
    for (int j = 0; j < 4; ++j) acc[i][j] = (f32x4){0.f, 0.f, 0.f, 0.f};

  auto SA = [&](int t, int bb, int kh) {
#pragma unroll
    for (int s = 0; s < ALs; ++s) gl16(aP[s] + t * 64 + kh * 32, &As[bb][kh][aL[s]]);
  };
  auto SB = [&](int t, int bb, int kh) {
#pragma unroll
    for (int s = 0; s < 2; ++s) gl16(bP[s] + t * 64 + kh * 32, &Bs[bb][kh][bL[s]]);
  };
#define BAR_()  __builtin_amdgcn_s_barrier()
#define LGKM_() do { asm volatile("s_waitcnt lgkmcnt(0)" ::: "memory"); \
                     __builtin_amdgcn_sched_barrier(0); } while (0)

  const int nt = K >> 6;
  SA(0, 0, 0); SB(0, 0, 0); SA(0, 0, 1); SB(0, 0, 1);
  if (nt > 1) { SA(1, 1, 0); SB(1, 1, 0); SA(1, 1, 1); }
  if (nt > 2) {
    if constexpr (ALs == 2) asm volatile("s_waitcnt vmcnt(6)" ::: "memory");
    else                    asm volatile("s_waitcnt vmcnt(4)" ::: "memory");
  } else {
    asm volatile("s_waitcnt vmcnt(0)" ::: "memory");
  }
  BAR_();

  for (int t = 0; t < nt; ++t) {
    const int b = t & 1, ob = b ^ 1;
    const bool s1 = (t + 1 < nt), s2 = (t + 2 < nt);
    bf16x8 af[RF], bf0, bf1;
    // phase 0: reads first, then stage (round-8 order)
#pragma unroll
    for (int i = 0; i < RF; ++i) af[i] = *(const bf16x8*)(&As[b][0][offA[i]]);
    bf0 = *(const bf16x8*)(&Bs[b][0][offB[0]]);
    bf1 = *(const bf16x8*)(&Bs[b][0][offB[1]]);
    if (s1) SB(t + 1, ob, 1);
    BAR_(); LGKM_();
    __builtin_amdgcn_s_setprio(1);
#pragma unroll
    for (int i = 0; i < RF; ++i) {
      acc[i][0] = __builtin_amdgcn_mfma_f32_16x16x32_bf16(af[i], bf0, acc[i][0], 0, 0, 0);
      acc[i][1] = __builtin_amdgcn_mfma_f32_16x16x32_bf16(af[i], bf1, acc[i][1], 0, 0, 0);
    }
    __builtin_amdgcn_s_setprio(0);
    BAR_();
    // phase 1
    bf0 = *(const bf16x8*)(&Bs[b][0][offB[2]]);
    bf1 = *(const bf16x8*)(&Bs[b][0][offB[3]]);
    if (s2) SA(t + 2, b, 0);
    BAR_(); LGKM_();
    __builtin_amdgcn_s_setprio(1);
#pragma unroll
    for (int i = 0; i < RF; ++i) {
      acc[i][2] = __builtin_amdgcn_mfma_f32_16x16x32_bf16(af[i], bf0, acc[i][2], 0, 0, 0);
      acc[i][3] = __builtin_amdgcn_mfma_f32_16x16x32_bf16(af[i], bf1, acc[i][3], 0, 0, 0);
    }
    __builtin_amdgcn_s_setprio(0);
    BAR_();
    // phase 2
#pragma unroll
    for (int i = 0; i < RF; ++i) af[i] = *(const bf16x8*)(&As[b][1][offA[i]]);
    bf0 = *(const bf16x8*)(&Bs[b][1][offB[0]]);
    bf1 = *(const bf16x8*)(&Bs[b][1][offB[1]]);
    if (s2) SB(t + 2, b, 0);
    BAR_(); LGKM_();
    __builtin_amdgcn_s_setprio(1);
#pragma unroll
    for (int i = 0; i < RF; ++i) {
      acc[i][0] = __builtin_amdgcn_mfma_f32_16x16x32_bf16(af[i], bf0, acc[i][0], 0, 0, 0);
      acc[i][1] = __builtin_amdgcn_mfma_f32_16x16x32_bf16(af[i], bf1, acc[i][1], 0, 0, 0);
    }
    __builtin_amdgcn_s_setprio(0);
    BAR_();
    // phase 3
    bf0 = *(const bf16x8*)(&Bs[b][1][offB[2]]);
    bf1 = *(const bf16x8*)(&Bs[b][1][offB[3]]);
    if (s2) SA(t + 2, b, 1);
    BAR_(); LGKM_();
    __builtin_amdgcn_s_setprio(1);
#pragma unroll
    for (int i = 0; i < RF; ++i) {
      acc[i][2] = __builtin_amdgcn_mfma_f32_16x16x32_bf16(af[i], bf0, acc[i][2], 0, 0, 0);
      acc[i][3] = __builtin_amdgcn_mfma_f32_16x16x32_bf16(af[i], bf1, acc[i][3], 0, 0, 0);
    }
    __builtin_amdgcn_s_setprio(0);
    if (t < nt - 2) {
      if constexpr (ALs == 2) asm volatile("s_waitcnt vmcnt(6)" ::: "memory");
      else                    asm volatile("s_waitcnt vmcnt(4)" ::: "memory");
    } else {
      asm volatile("s_waitcnt vmcnt(0)" ::: "memory");
    }
    BAR_();
  }

  // ---- epilogue ----
  if constexpr (sizeof(TO) == 2) {
    float* sc = (float*)(&As[0][0][0]) + (size_t)wid * (16 * 72);
    const int rr = lane >> 3, cc8 = (lane & 7) * 8;
#pragma unroll
    for (int i = 0; i < RF; ++i) {
      const int row0 = m0 + wr * (BM_T / 2) + i * 16;
#pragma unroll
      for (int j = 0; j < 4; ++j) {
        const float bb = bias[n0 + wc * 64 + j * 16 + l16];
#pragma unroll
        for (int e = 0; e < 4; ++e) {
          float vv = acc[i][j][e] + bb;
          if (EPI == EPI_SILU) { float c2 = fminf(fmaxf(vv, -10.f), 10.f); vv = vv / (1.f + __expf(-c2)); }
          sc[(lq * 4 + e) * 72 + j * 16 + l16] = vv;
        }
      }
      asm volatile("s_waitcnt lgkmcnt(0)" ::: "memory");
      __builtin_amdgcn_sched_barrier(0);
#pragma unroll
      for (int q = 0; q < 2; ++q) {
        const int row = row0 + rr + q * 8;
        const size_t base = (size_t)row * N + n0 + wc * 64 + cc8;
        f32x4 a0 = *(const f32x4*)(sc + (rr + q * 8) * 72 + cc8);
        f32x4 a1 = *(const f32x4*)(sc + (rr + q * 8) * 72 + cc8 + 4);
        bf16x8 o;
        if constexpr (EPI == EPI_RES) {
          if constexpr (sizeof(TE) == 4) {
            f32x4 x0 = *(const f32x4*)((const float*)extra + base);
            f32x4 x1 = *(const f32x4*)((const float*)extra + base + 4);
#pragma unroll
            for (int e = 0; e < 4; ++e) { o[e] = (bf16_t)(a0[e] + x0[e]); o[4 + e] = (bf16_t)(a1[e] + x1[e]); }
          } else {
            bf16x8 x8 = *(const bf16x8*)((const bf16_t*)extra + base);
#pragma unroll
            for (int e = 0; e < 4; ++e) { o[e] = (bf16_t)(a0[e] + (float)x8[e]); o[4 + e] = (bf16_t)(a1[e] + (float)x8[4 + e]); }
          }
        } else if constexpr (EPI == EPI_MUL) {
          bf16x8 x8 = *(const bf16x8*)((const bf16_t*)extra + base);
#pragma unroll
          for (int e = 0; e < 4; ++e) { o[e] = (bf16_t)(a0[e] * (float)x8[e]); o[4 + e] = (bf16_t)(a1[e] * (float)x8[4 + e]); }
        } else {
#pragma unroll
          for (int e = 0; e < 4; ++e) { o[e] = (bf16_t)a0[e]; o[4 + e] = (bf16_t)a1[e]; }
        }
        *(bf16x8*)((bf16_t*)out + base) = o;
      }
      asm volatile("s_waitcnt lgkmcnt(0)" ::: "memory");
      __builtin_amdgcn_sched_barrier(0);
    }
  } else {
#pragma unroll
    for (int j = 0; j < 4; ++j) {
      const int col = n0 + wc * 64 + j * 16 + l16;
      const float bb = bias[col];
#pragma unroll
      for (int i = 0; i < RF; ++i) {
        const int row0 = m0 + wr * (BM_T / 2) + i * 16 + lq * 4;
#pragma unroll
        for (int e = 0; e < 4; ++e) {
          const size_t idx = (size_t)(row0 + e) * N + col;
          float vv = acc[i][j][e] + bb;
          if (EPI == EPI_RES)       vv += (float)extra[idx];
          else if (EPI == EPI_SILU) { float c2 = fminf(fmaxf(vv, -10.f), 10.f); vv = vv / (1.f + __expf(-c2)); }
          else if (EPI == EPI_MUL)  vv *= (float)extra[idx];
          out[idx] = (TO)vv;
        }
      }
    }
  }
#undef BAR_
#undef LGKM_
}

// ======= gemm3b (round-11 proven, 848 TF): 128x128, BK=32, 4 waves, 3 LDS bufs =======
template<int EPI, typename TE, typename TO>
__global__ __launch_bounds__(256, 4)
void gemm3b(const bf16_t* __restrict__ A, const bf16_t* __restrict__ Bt,
            const float* __restrict__ bias, const TE* __restrict__ extra,
            TO* __restrict__ out, int M, int N, int K)
{
  __shared__ __align__(16) bf16_t As[3][128 * 32];
  __shared__ __align__(16) bf16_t Bs[3][128 * 32];
  const int tid = threadIdx.x, lane = tid & 63, wid = tid >> 6;
  const int wr = wid >> 1, wc = wid & 1;
  const int l16 = lane & 15, lq = lane >> 4;
  int m0, n0; xcd_swz(128, 128, m0, n0);

  const bf16_t* aP[2]; const bf16_t* bP[2]; int sL[2];
#pragma unroll
  for (int s = 0; s < 2; ++s) {
    const int c = s * 256 + tid;
    const int row = c >> 2, pos = c & 3;
    const int g = pos ^ ((row >> 1) & 3);
    aP[s] = A  + (size_t)(m0 + row) * K + g * 8;
    bP[s] = Bt + (size_t)(n0 + row) * K + g * 8;
    sL[s] = (s * 256 + wid * 64) * 8;
  }

  int offA[4], offB[4];
#pragma unroll
  for (int i = 0; i < 4; ++i) {
    const int r = wr * 64 + i * 16 + l16;
    offA[i] = r * 32 + ((lq ^ ((r >> 1) & 3)) * 8);
  }
#pragma unroll
  for (int j = 0; j < 4; ++j) {
    const int r = wc * 64 + j * 16 + l16;
    offB[j] = r * 32 + ((lq ^ ((r >> 1) & 3)) * 8);
  }

  f32x4 acc[4][4];
#pragma unroll
  for (int i = 0; i < 4; ++i)
#pragma unroll
    for (int j = 0; j < 4; ++j) acc[i][j] = (f32x4){0.f, 0.f, 0.f, 0.f};

  auto STAGE = [&](int t, int b) {
    gl16(aP[0] + t * 32, &As[b][sL[0]]);
    gl16(aP[1] + t * 32, &As[b][sL[1]]);
    gl16(bP[0] + t * 32, &Bs[b][sL[0]]);
    gl16(bP[1] + t * 32, &Bs[b][sL[1]]);
  };

  const int nt = K >> 5;
  STAGE(0, 0);
  STAGE(1, 1);
  if (nt > 1) asm volatile("s_waitcnt vmcnt(4)" ::: "memory");
  else        asm volatile("s_waitcnt vmcnt(0)" ::: "memory");
  __builtin_amdgcn_s_barrier();

  int b = 0;
  for (int t = 0; t < nt; ++t) {
    bf16x8 af[4], bfr[4];
#pragma unroll
    for (int i = 0; i < 4; ++i) af[i]  = *(const bf16x8*)(&As[b][offA[i]]);
#pragma unroll
    for (int j = 0; j < 4; ++j) bfr[j] = *(const bf16x8*)(&Bs[b][offB[j]]);
    if (t + 2 < nt) {
      STAGE(t + 2, (b + 2) % 3);
      asm volatile("s_waitcnt vmcnt(4)" ::: "memory");
    } else {
      asm volatile("s_waitcnt vmcnt(0)" ::: "memory");
    }
    __builtin_amdgcn_s_barrier();
    asm volatile("s_waitcnt lgkmcnt(0)" ::: "memory");
    __builtin_amdgcn_sched_barrier(0);
    __builtin_amdgcn_s_setprio(1);
#pragma unroll
    for (int i = 0; i < 4; ++i)
#pragma unroll
      for (int j = 0; j < 4; ++j)
        acc[i][j] = __builtin_amdgcn_mfma_f32_16x16x32_bf16(af[i], bfr[j], acc[i][j], 0, 0, 0);
    __builtin_amdgcn_s_setprio(0);
    __builtin_amdgcn_s_barrier();
    b = (b + 1) % 3;
  }

  // ---- epilogue ----
  if constexpr (sizeof(TO) == 2) {
    float* sc = (float*)(&As[0][0]) + (size_t)wid * (16 * 72);
    const int rr = lane >> 3, cc8 = (lane & 7) * 8;
#pragma unroll
    for (int i = 0; i < 4; ++i) {
      const int row0 = m0 + wr * 64 + i * 16;
#pragma unroll
      for (int j = 0; j < 4; ++j) {
        const float bb = bias[n0 + wc * 64 + j * 16 + l16];
#pragma unroll
        for (int e = 0; e < 4; ++e) {
          float vv = acc[i][j][e] + bb;
          if (EPI == EPI_SILU) { float c2 = fminf(fmaxf(vv, -10.f), 10.f); vv = vv / (1.f + __expf(-c2)); }
          sc[(lq * 4 + e) * 72 + j * 16 + l16] = vv;
        }
      }
      asm volatile("s_waitcnt lgkmcnt(0)" ::: "memory");
      __builtin_amdgcn_sched_barrier(0);
#pragma unroll
      for (int q = 0; q < 2; ++q) {
        const int row = row0 + rr + q * 8;
        const size_t base = (size_t)row * N + n0 + wc * 64 + cc8;
        f32x4 a0 = *(const f32x4*)(sc + (rr + q * 8) * 72 + cc8);
        f32x4 a1 = *(const f32x4*)(sc + (rr + q * 8) * 72 + cc8 + 4);
        bf16x8 o;
        if constexpr (EPI == EPI_RES) {
          if constexpr (sizeof(TE) == 4) {
            f32x4 x0 = *(const f32x4*)((const float*)extra + base);
            f32x4 x1 = *(const f32x4*)((const float*)extra + base + 4);
#pragma unroll
            for (int e = 0; e < 4; ++e) { o[e] = (bf16_t)(a0[e] + x0[e]); o[4 + e] = (bf16_t)(a1[e] + x1[e]); }
          } else {
            bf16x8 x8 = *(const bf16x8*)((const bf16_t*)extra + base);
#pragma unroll
            for (int e = 0; e < 4; ++e) { o[e] = (bf16_t)(a0[e] + (float)x8[e]); o[4 + e] = (bf16_t)(a1[e] + (float)x8[4 + e]); }
          }
        } else if constexpr (EPI == EPI_MUL) {
          bf16x8 x8 = *(const bf16x8*)((const bf16_t*)extra + base);
#pragma unroll
          for (int e = 0; e < 4; ++e) { o[e] = (bf16_t)(a0[e] * (float)x8[e]); o[4 + e] = (bf16_t)(a1[e] * (float)x8[4 + e]); }
        } else {
#pragma unroll
          for (int e = 0; e < 4; ++e) { o[e] = (bf16_t)a0[e]; o[4 + e] = (bf16_t)a1[e]; }
        }
        *(bf16x8*)((bf16_t*)out + base) = o;
      }
      asm volatile("s_waitcnt lgkmcnt(0)" ::: "memory");
      __builtin_amdgcn_sched_barrier(0);
    }
  } else {
#pragma unroll
    for (int j = 0; j < 4; ++j) {
      const int col = n0 + wc * 64 + j * 16 + l16;
      const float bb = bias[col];
#pragma unroll
      for (int i = 0; i < 4; ++i) {
        const int row0 = m0 + wr * 64 + i * 16 + lq * 4;
#pragma unroll
        for (int e = 0; e < 4; ++e) {
          const size_t idx = (size_t)(row0 + e) * N + col;
          float vv = acc[i][j][e] + bb;
          if (EPI == EPI_RES)       vv += (float)extra[idx];
          else if (EPI == EPI_SILU) { float c2 = fminf(fmaxf(vv, -10.f), 10.f); vv = vv / (1.f + __expf(-c2)); }
          else if (EPI == EPI_MUL)  vv *= (float)extra[idx];
          out[idx] = (TO)vv;
        }
      }
    }
  }
}

// ------- fallback GEMM (f32 weights, round-1 proven) -------
template<int EPI, typename TE, typename TO>
__global__ __launch_bounds__(256)
void gemm_kernel(const bf16_t* __restrict__ A, const float* __restrict__ W,
                 const float* __restrict__ bias, const TE* __restrict__ extra,
                 TO* __restrict__ out, int M, int N, int K)
{
  __shared__ bf16_t As[128][40];
  __shared__ bf16_t Bs[128][40];
  const int tid  = threadIdx.x;
  const int lane = tid & 63, wid = tid >> 6;
  const int wr = wid >> 1, wc = wid & 1;
  const int l16 = lane & 15, lq = lane >> 4;
  const int m0 = blockIdx.y * 128, n0 = blockIdx.x * 128;

  f32x4 acc[4][4];
#pragma unroll
  for (int i = 0; i < 4; ++i)
#pragma unroll
    for (int j = 0; j < 4; ++j) acc[i][j] = (f32x4){0.f, 0.f, 0.f, 0.f};

  const int ar = tid >> 1, ah = tid & 1;
  const int kk = tid & 31, cc = tid >> 5;

  for (int k0 = 0; k0 < K; k0 += 32) {
    const bf16_t* asrc = A + (size_t)(m0 + ar) * K + k0 + ah * 16;
    *(bf16x8*)(&As[ar][ah * 16])     = *(const bf16x8*)(asrc);
    *(bf16x8*)(&As[ar][ah * 16 + 8]) = *(const bf16x8*)(asrc + 8);
    const float* wsrc = W + (size_t)(k0 + kk) * N + n0;
#pragma unroll
    for (int it = 0; it < 2; ++it) {
      const int c = cc * 8 + it * 64;
      f32x4 wa = *(const f32x4*)(wsrc + c);
      f32x4 wb = *(const f32x4*)(wsrc + c + 4);
#pragma unroll
      for (int e = 0; e < 4; ++e) {
        Bs[c + e][kk]     = (bf16_t)wa[e];
        Bs[c + 4 + e][kk] = (bf16_t)wb[e];
      }
    }
    __syncthreads();
    bf16x8 af[4], bfr[4];
#pragma unroll
    for (int i = 0; i < 4; ++i) {
      const bf16_t* p = &As[wr * 64 + i * 16 + l16][lq * 4];
      af[i] = mk8(*(const bf16x4*)p, *(const bf16x4*)(p + 16));
    }
#pragma unroll
    for (int j = 0; j < 4; ++j) {
      const bf16_t* p = &Bs[wc * 64 + j * 16 + l16][lq * 4];
      bfr[j] = mk8(*(const bf16x4*)p, *(const bf16x4*)(p + 16));
    }
#pragma unroll
    for (int i = 0; i < 4; ++i)
#pragma unroll
      for (int j = 0; j < 4; ++j)
        acc[i][j] = __builtin_amdgcn_mfma_f32_16x16x32_bf16(af[i], bfr[j], acc[i][j], 0, 0, 0);
    __syncthreads();
  }

#pragma unroll
  for (int j = 0; j < 4; ++j) {
    const int col = n0 + wc * 64 + j * 16 + l16;
    const float bb = bias[col];
#pragma unroll
    for (int i = 0; i < 4; ++i) {
      const int row0 = m0 + wr * 64 + i * 16 + lq * 4;
#pragma unroll
      for (int e = 0; e < 4; ++e) {
        const size_t idx = (size_t)(row0 + e) * N + col;
        float vv = acc[i][j][e] + bb;
        if (EPI == EPI_RES)       vv += (float)extra[idx];
        else if (EPI == EPI_SILU) { float c2 = fminf(fmaxf(vv, -10.f), 10.f); vv = vv / (1.f + __expf(-c2)); }
        else if (EPI == EPI_MUL)  vv *= (float)extra[idx];
        out[idx] = (TO)vv;
      }
    }
  }
}

// ---- Flash attention v4: QBLK=128 (8 waves), swapped QK^T, pipelined K/V staging ----
__global__ __launch_bounds__(512)
void attn_kernel(const bf16_t* __restrict__ q, const bf16_t* __restrict__ k,
                 const bf16_t* __restrict__ v, bf16_t* __restrict__ ctx,
                 int q_ld, int kv_ld)
{
  __shared__ __align__(16) bf16_t Ks[2][64 * 128];  // 32 KB, chunk-XOR swizzled
  __shared__ __align__(16) bf16_t Vt[128][72];      // 18.4 KB, [hd][kv] transposed

  const int tid = threadIdx.x, lane = tid & 63, wid = tid >> 6;  // wid 0..7
  const int l16 = lane & 15, lq = lane >> 4;
  const int bh = blockIdx.y;
  const int b = bh >> 4, h = bh & 15;
  const int kh = h >> 2;
  const float scale = 0.08838834764831845f;

  const int vr = tid & 63, vo = (tid >> 6) * 8;

  for (int pass = 0; pass < 2; ++pass) {
    const int qt = pass ? blockIdx.x : (15 - blockIdx.x);
    const int qbase = qt * 128;
    const int qrow = qbase + wid * 16 + l16;

    const bf16_t* qp = q + (size_t)(b * T_SEQ + qrow) * q_ld + h * HDIM;
    bf16x8 bq[4];
#pragma unroll
    for (int s = 0; s < 4; ++s) bq[s] = *(const bf16x8*)(qp + s * 32 + lq * 8);

    float m_r = -1e30f, l_r = 0.f;
    f32x4 acc_o[8];
#pragma unroll
    for (int jh = 0; jh < 8; ++jh) acc_o[jh] = (f32x4){0.f, 0.f, 0.f, 0.f};

    const int ntiles = (qbase + 128) >> 6;

    bf16x8 vregs[2];
#pragma unroll
    for (int it = 0; it < 2; ++it) {
      const int c = it * 512 + tid;
      const int kvr = c >> 4, pos = c & 15;
      gl16(k + (size_t)(b * T_SEQ + kvr) * kv_ld + kh * HDIM + (pos ^ (kvr & 7)) * 8,
           &Ks[0][(it * 512 + wid * 64) * 8]);
    }
#pragma unroll
    for (int it = 0; it < 2; ++it)
      vregs[it] = *(const bf16x8*)(v + (size_t)(b * T_SEQ + vr) * kv_ld + kh * HDIM + vo + it * 64);

    int cur = 0;
    for (int t = 0; t < ntiles; ++t) {
      const int kb = t * 64;
#pragma unroll
      for (int it = 0; it < 2; ++it) {
#pragma unroll
        for (int e = 0; e < 8; ++e) Vt[vo + it * 64 + e][vr] = vregs[it][e];
      }
      if (t + 1 < ntiles) {
        const int kb2 = kb + 64;
#pragma unroll
        for (int it = 0; it < 2; ++it) {
          const int c = it * 512 + tid;
          const int kvr = c >> 4, pos = c & 15;
          gl16(k + (size_t)(b * T_SEQ + kb2 + kvr) * kv_ld + kh * HDIM + (pos ^ (kvr & 7)) * 8,
               &Ks[cur ^ 1][(it * 512 + wid * 64) * 8]);
        }
#pragma unroll
        for (int it = 0; it < 2; ++it)
          vregs[it] = *(const bf16x8*)(v + (size_t)(b * T_SEQ + kb2 + vr) * kv_ld + kh * HDIM + vo + it * 64);
      }
      asm volatile("s_waitcnt lgkmcnt(0)" ::: "memory");
      __builtin_amdgcn_s_barrier();
      __builtin_amdgcn_sched_barrier(0);

      f32x4 sf[4];
#pragma unroll
      for (int j = 0; j < 4; ++j) {
        sf[j] = (f32x4){0.f, 0.f, 0.f, 0.f};
        const int kvr = j * 16 + l16;
#pragma unroll
        for (int s = 0; s < 4; ++s) {
          bf16x8 ak = *(const bf16x8*)(&Ks[cur][kvr * 128 + (((s * 4 + lq) ^ (kvr & 7)) * 8)]);
          sf[j] = __builtin_amdgcn_mfma_f32_16x16x32_bf16(ak, bq[s], sf[j], 0, 0, 0);
        }
      }

      float p[4][4];
      float tmax = -1e30f;
#pragma unroll
      for (int j = 0; j < 4; ++j)
#pragma unroll
        for (int e = 0; e < 4; ++e) {
          const int kvc = kb + j * 16 + lq * 4 + e;
          float sv = sf[j][e] * scale;
          sv = fminf(fmaxf(sv, -100.f), 100.f);
          if (kvc > qrow) sv = -1e30f;
          p[j][e] = sv;
          tmax = fmaxf(tmax, sv);
        }
      tmax = fmaxf(tmax, __shfl_xor(tmax, 16));
      tmax = fmaxf(tmax, __shfl_xor(tmax, 32));
      const float mnew = fmaxf(m_r, tmax);
      const float resc = __expf(m_r - mnew);
      m_r = mnew;
      float rsum = 0.f;
#pragma unroll
      for (int j = 0; j < 4; ++j)
#pragma unroll
        for (int e = 0; e < 4; ++e) {
          p[j][e] = __expf(p[j][e] - m_r);
          rsum += p[j][e];
        }
      rsum += __shfl_xor(rsum, 16);
      rsum += __shfl_xor(rsum, 32);
      l_r = l_r * resc + rsum;

      float resc4[4];
#pragma unroll
      for (int e = 0; e < 4; ++e) resc4[e] = __shfl(resc, lq * 4 + e);
#pragma unroll
      for (int jh = 0; jh < 8; ++jh)
#pragma unroll
        for (int e = 0; e < 4; ++e) acc_o[jh][e] *= resc4[e];

      bf16x8 pa[2];
#pragma unroll
      for (int sk = 0; sk < 2; ++sk) {
        bf16x4 lo, hi;
#pragma unroll
        for (int e = 0; e < 4; ++e) { lo[e] = (bf16_t)p[2 * sk][e]; hi[e] = (bf16_t)p[2 * sk + 1][e]; }
        pa[sk] = mk8(lo, hi);
      }
#pragma unroll
      for (int jh = 0; jh < 8; ++jh) {
#pragma unroll
        for (int sk = 0; sk < 2; ++sk) {
          const bf16_t* pV = &Vt[jh * 16 + l16][sk * 32 + lq * 4];
          bf16x8 bv2 = mk8(*(const bf16x4*)pV, *(const bf16x4*)(pV + 16));
          acc_o[jh] = __builtin_amdgcn_mfma_f32_16x16x32_bf16(pa[sk], bv2, acc_o[jh], 0, 0, 0);
        }
      }
      __builtin_amdgcn_s_barrier();
      cur ^= 1;
    }

    float l4[4];
#pragma unroll
    for (int e = 0; e < 4; ++e) l4[e] = __shfl(l_r, lq * 4 + e);
    bf16_t* op = ctx + (size_t)(b * T_SEQ + qbase + wid * 16) * D_MODEL + h * HDIM;
#pragma unroll
    for (int jh = 0; jh < 8; ++jh)
#pragma unroll
      for (int e = 0; e < 4; ++e)
        op[(size_t)(lq * 4 + e) * D_MODEL + jh * 16 + l16] = (bf16_t)(acc_o[jh][e] / l4[e]);
  }
}

// ---------------- launcher ----------------
extern "C" void kernel_launch(void* const* d_in, const int* in_sizes, int n_in,
                              void* d_out, int out_size, void* d_ws, size_t ws_size,
                              hipStream_t stream)
{
  const float* x   = (const float*)d_in[0];
  const float* Wq  = (const float*)d_in[2];
  const float* bq  = (const float*)d_in[3];
  const float* Wk  = (const float*)d_in[4];
  const float* bk  = (const float*)d_in[5];
  const float* Wv  = (const float*)d_in[6];
  const float* bv  = (const float*)d_in[7];
  const float* Wo  = (const float*)d_in[8];
  const float* bo  = (const float*)d_in[9];
  const float* g1  = (const float*)d_in[10];
  const float* b1n = (const float*)d_in[11];
  const float* g2  = (const float*)d_in[12];
  const float* b2n = (const float*)d_in[13];
  const float* gf  = (const float*)d_in[14];
  const float* bfn = (const float*)d_in[15];
  const float* W1  = (const float*)d_in[16];
  const float* bb1 = (const float*)d_in[17];
  const float* W2  = (const float*)d_in[18];
  const float* bb2 = (const float*)d_in[19];
  const float* W3  = (const float*)d_in[20];
  const float* bb3 = (const float*)d_in[21];
  float* out = (float*)d_out;

  char* ws = (char*)d_ws;
  size_t off = 0;
  auto alloc = [&](size_t bytes) -> void* {
    void* p = ws + off; off += (bytes + 255) & ~(size_t)255; return p;
  };
  const dim3 blk(256);

  // ---- fast-path workspace layout ----
  bf16_t* Wt_qkv = (bf16_t*)alloc((size_t)QKVN * D_MODEL * 2);
  bf16_t* Wt_o   = (bf16_t*)alloc((size_t)D_MODEL * D_MODEL * 2);
  bf16_t* Wt1    = (bf16_t*)alloc((size_t)FDIM * D_MODEL * 2);
  bf16_t* Wt2    = (bf16_t*)alloc((size_t)FDIM * D_MODEL * 2);
  bf16_t* Wt3    = (bf16_t*)alloc((size_t)D_MODEL * FDIM * 2);
  float*  bqkv   = (float*)alloc((size_t)QKVN * 4);
  bf16_t* hbuf   = (bf16_t*)alloc((size_t)NROWS * D_MODEL * 2);
  bf16_t* qkvbuf = (bf16_t*)alloc((size_t)NROWS * QKVN * 2);
  bf16_t* rbuf   = (bf16_t*)alloc((size_t)NROWS * D_MODEL * 2);
  bf16_t* h2buf  = (bf16_t*)alloc((size_t)NROWS * D_MODEL * 2);
  const size_t core = off;

  if (core <= ws_size) {
    size_t avail = ws_size - core;
    int chunk = (int)((avail / ((size_t)FDIM * 2)) & ~(size_t)255);
    bf16_t* gbuf;
    if (chunk >= 256) { gbuf = (bf16_t*)(ws + core); if (chunk > NROWS) chunk = NROWS; }
    else              { gbuf = qkvbuf; chunk = 1536; }  // 1536 % 256 == 0
    bf16_t* x1buf = qkvbuf;

    transpose_w<<<dim3(32, 32),  blk, 0, stream>>>(Wq, Wt_qkv, D_MODEL, 2048);
    transpose_w<<<dim3(8, 32),   blk, 0, stream>>>(Wk, Wt_qkv + (size_t)2048 * D_MODEL, D_MODEL, 512);
    transpose_w<<<dim3(8, 32),   blk, 0, stream>>>(Wv, Wt_qkv + (size_t)2560 * D_MODEL, D_MODEL, 512);
    transpose_w<<<dim3(32, 32),  blk, 0, stream>>>(Wo, Wt_o, D_MODEL, D_MODEL);
    transpose_w<<<dim3(128, 32), blk, 0, stream>>>(W1, Wt1, D_MODEL, FDIM);
    transpose_w<<<dim3(128, 32), blk, 0, stream>>>(W2, Wt2, D_MODEL, FDIM);
    transpose_w<<<dim3(32, 128), blk, 0, stream>>>(W3, Wt3, FDIM, D_MODEL);
    concat_bias<<<12, blk, 0, stream>>>(bq, bk, bv, bqkv);

    ln_kernel<float><<<NROWS, blk, 0, stream>>>(x, g1, b1n, hbuf);
    gemm3b<EPI_NONE, bf16_t, bf16_t><<<dim3(QKVN / 128, NROWS / 128), blk, 0, stream>>>(
        hbuf, Wt_qkv, bqkv, nullptr, qkvbuf, NROWS, QKVN, D_MODEL);
    attn_kernel<<<dim3(8, 32), 512, 0, stream>>>(
        qkvbuf, qkvbuf + 2048, qkvbuf + 2560, hbuf, QKVN, QKVN);
    gemm3b<EPI_RES, float, bf16_t><<<dim3(D_MODEL / 128, NROWS / 128), blk, 0, stream>>>(
        hbuf, Wt_o, bo, x, x1buf, NROWS, D_MODEL, D_MODEL);
    ln2_fused<<<NROWS, blk, 0, stream>>>(x1buf, g2, b2n, gf, bfn, rbuf, h2buf);

    for (int r0 = 0; r0 < NROWS; r0 += chunk) {
      const int rows = (NROWS - r0 < chunk) ? (NROWS - r0) : chunk;
      gemm8p<EPI_SILU, 256, bf16_t, bf16_t><<<dim3(FDIM / 256, rows / 256), 512, 0, stream>>>(
          h2buf + (size_t)r0 * D_MODEL, Wt1, bb1, nullptr, gbuf, rows, FDIM, D_MODEL);
      gemm8p<EPI_MUL, 256, bf16_t, bf16_t><<<dim3(FDIM / 256, rows / 256), 512, 0, stream>>>(
          h2buf + (size_t)r0 * D_MODEL, Wt2, bb2, gbuf, gbuf, rows, FDIM, D_MODEL);
      gemm3b<EPI_RES, bf16_t, float><<<dim3(D_MODEL / 128, rows / 128), blk, 0, stream>>>(
          gbuf, Wt3, bb3, rbuf + (size_t)r0 * D_MODEL, out + (size_t)r0 * D_MODEL, rows, D_MODEL, FDIM);
    }
    return;
  }

  // ---- fallback: round-1 proven path (f32 weights in GEMM) ----
  off = 0;
  const size_t DBYTES = (size_t)NROWS * D_MODEL * 2;
  bf16_t* fhbuf  = (bf16_t*)alloc(DBYTES);
  bf16_t* fqbuf  = (bf16_t*)alloc(DBYTES);
  bf16_t* fkbuf  = (bf16_t*)alloc((size_t)NROWS * KVD * 2);
  bf16_t* fvbuf  = (bf16_t*)alloc((size_t)NROWS * KVD * 2);
  bf16_t* frbuf  = (bf16_t*)alloc(DBYTES);
  bf16_t* fh2buf = (bf16_t*)alloc(DBYTES);
  const size_t base = off;
  size_t avail = (ws_size > base) ? (ws_size - base) : 0;
  int chunk = (int)((avail / ((size_t)FDIM * 2)) & ~(size_t)127);
  bf16_t* gbuf;
  if (chunk >= 128) { gbuf = (bf16_t*)(ws + base); if (chunk > NROWS) chunk = NROWS; }
  else              { gbuf = fqbuf; chunk = 1024; }

  ln_kernel<float><<<NROWS, blk, 0, stream>>>(x, g1, b1n, fhbuf);
  gemm_kernel<EPI_NONE, bf16_t, bf16_t><<<dim3(16, 32), blk, 0, stream>>>(fhbuf, Wq, bq, nullptr, fqbuf, NROWS, 2048, 2048);
  gemm_kernel<EPI_NONE, bf16_t, bf16_t><<<dim3(4, 32),  blk, 0, stream>>>(fhbuf, Wk, bk, nullptr, fkbuf, NROWS, 512, 2048);
  gemm_kernel<EPI_NONE, bf16_t, bf16_t><<<dim3(4, 32),  blk, 0, stream>>>(fhbuf, Wv, bv, nullptr, fvbuf, NROWS, 512, 2048);
  attn_kernel<<<dim3(8, 32), 512, 0, stream>>>(fqbuf, fkbuf, fvbuf, fhbuf, 2048, 512);
  gemm_kernel<EPI_RES, float, bf16_t><<<dim3(16, 32), blk, 0, stream>>>(fhbuf, Wo, bo, x, fqbuf, NROWS, 2048, 2048);
  ln_kernel<bf16_t><<<NROWS, blk, 0, stream>>>(fqbuf, g2, b2n, frbuf);
  ln_kernel<bf16_t><<<NROWS, blk, 0, stream>>>(frbuf, gf, bfn, fh2buf);
  for (int r0 = 0; r0 < NROWS; r0 += chunk) {
    const int rows = (NROWS - r0 < chunk) ? (NROWS - r0) : chunk;
    gemm_kernel<EPI_SILU, bf16_t, bf16_t><<<dim3(64, rows / 128), blk, 0, stream>>>(
        fh2buf + (size_t)r0 * D_MODEL, W1, bb1, nullptr, gbuf, rows, FDIM, 2048);
    gemm_kernel<EPI_MUL, bf16_t, bf16_t><<<dim3(64, rows / 128), blk, 0, stream>>>(
        fh2buf + (size_t)r0 * D_MODEL, W2, bb2, gbuf, gbuf, rows, FDIM, 2048);
    gemm_kernel<EPI_RES, bf16_t, float><<<dim3(16, rows / 128), blk, 0, stream>>>(
        gbuf, W3, bb3, frbuf + (size_t)r0 * D_MODEL, out + (size_t)r0 * D_MODEL, rows, 2048, FDIM);
  }
}